// Round 5
// baseline (133.728 us; speedup 1.0000x reference)
//
#include <hip/hip_runtime.h>
#include <stdint.h>

#define D 128
#define TM 64
#define GRID 512        // 2 blocks/CU * 256 CU (LDS-capped)
#define NTHREADS 256
#define PPS 17          // pp row stride (pad kills bank conflicts)

typedef float f32x4 __attribute__((ext_vector_type(4)));
typedef short s16x8 __attribute__((ext_vector_type(8)));
typedef uint32_t u32x2 __attribute__((ext_vector_type(2)));
typedef uint32_t u32x4 __attribute__((ext_vector_type(4)));

__device__ __forceinline__ uint32_t f2bf_u(float f) {
    union { float f; uint32_t u; } v; v.f = f;
    return (v.u + 0x7fffu + ((v.u >> 16) & 1u)) >> 16;   // RNE
}
__device__ __forceinline__ short f2bf(float f) { return (short)f2bf_u(f); }
__device__ __forceinline__ uint32_t cvt_pk_bf16(float lo, float hi) {
    uint32_t r;
    asm("v_cvt_pk_bf16_f32 %0, %1, %2" : "=v"(r) : "v"(lo), "v"(hi));
    return r;
}
// async global->LDS, 16B per lane; LDS dest is wave-uniform base + lane*16
__device__ __forceinline__ void gld16(const float* g, float* l) {
    __builtin_amdgcn_global_load_lds(
        (const __attribute__((address_space(1))) void*)g,
        (__attribute__((address_space(3))) void*)l, 16, 0, 0);
}

__global__ __launch_bounds__(NTHREADS, 2)
void gate_agg_kernel(const float* __restrict__ X,
                     const int* __restrict__ bidx,
                     const float* __restrict__ W1,
                     const float* __restrict__ b1,
                     const float* __restrict__ W2,
                     const float* __restrict__ b2,
                     float* __restrict__ out,
                     int NT)
{
    // fp32 X tiles, double-buffered. Linear LDS layout; data is source-swizzled:
    // LDS(row, chunk c) holds global 16B-chunk (c ^ (row&15)) of that row.
    __shared__ float fbuf[2][TM * D];      // 2 x 32 KB
    __shared__ float pp[64 * PPS];         // phase-2 partials [row][16]
    __shared__ u32x2 gidL[TM];             // {gate bits, seg}

    const int tid = threadIdx.x;
    const int l = tid & 63;
    const int w = tid >> 6;
    const int l15 = l & 15;
    const int lk = l >> 4;

    // ---- one-time: W1 B-fragments for this wave's 2 col-tiles -> registers
    s16x8 bfr[2][4];
    #pragma unroll
    for (int j = 0; j < 2; ++j) {
        const int n = (2 * w + j) * 16 + l15;
        #pragma unroll
        for (int kt = 0; kt < 4; ++kt) {
            #pragma unroll
            for (int e = 0; e < 8; ++e)
                bfr[j][kt][e] = f2bf(W1[(kt * 32 + lk * 8 + e) * D + n]);
        }
    }
    float b1v[2], w2v[2];
    #pragma unroll
    for (int j = 0; j < 2; ++j) {
        b1v[j] = b1[(2 * w + j) * 16 + l15];
        w2v[j] = W2[(2 * w + j) * 16 + l15];
    }
    const float b2s = b2[0];

    // balanced contiguous tile range
    const int q = NT / GRID, rem = NT % GRID;
    int t0, t1;
    if ((int)blockIdx.x < rem) { t0 = blockIdx.x * (q + 1); t1 = t0 + q + 1; }
    else { t0 = rem * (q + 1) + ((int)blockIdx.x - rem) * q; t1 = t0 + q; }

    // phase-3 ownership: 4 cols x 8 rows per thread
    const int cc = tid & 31;
    const int rg = tid >> 5;
    float acc3[4] = {0.f, 0.f, 0.f, 0.f};
    int cur = -1;

    // gload geometry: wave w, inst i covers rows 16w+2i .. +1 (1 KB linear)
    const int lrh = l >> 5;        // row within pair
    const int lch = l & 31;        // 16B chunk within row

    // ---- prologue: issue tile t0's loads into buffer 0
    if (t0 < t1) {
        const float* xg = X + (size_t)t0 * TM * D;
        #pragma unroll
        for (int i = 0; i < 8; ++i) {
            const int r = 16 * w + 2 * i + lrh;
            gld16(xg + r * D + ((lch ^ (r & 15)) << 2),
                  &fbuf[0][(16 * w + 2 * i) * D]);
        }
    }

    int cb = 0;   // current-buffer toggle (prologue loaded fbuf[0])
    for (int t = t0; t < t1; ++t, cb ^= 1) {
        // ---- top: tile t arrived (only t's loads outstanding) ----
        asm volatile("s_waitcnt vmcnt(0)" ::: "memory");
        __builtin_amdgcn_s_barrier();

        // bidx for tile t (used at phase 2b, long latency budget)
        int ridx = 0;
        if (tid < TM) ridx = bidx[(size_t)t * TM + tid];

        // ---- issue tile t+1 -> other buffer (in flight all iteration) ----
        if (t + 1 < t1) {
            const float* xg = X + (size_t)(t + 1) * TM * D;
            #pragma unroll
            for (int i = 0; i < 8; ++i) {
                const int r = 16 * w + 2 * i + lrh;
                gld16(xg + r * D + ((lch ^ (r & 15)) << 2),
                      &fbuf[cb ^ 1][(16 * w + 2 * i) * D]);
            }
        }

        const float* fb = fbuf[cb];

        // ---- phase 1: h = relu(X@W1+b1); wave owns 32 cols x 64 rows ----
        f32x4 acc[4][2];
        #pragma unroll
        for (int rf = 0; rf < 4; ++rf) { acc[rf][0] = (f32x4)0.f; acc[rf][1] = (f32x4)0.f; }

        #pragma unroll
        for (int kt = 0; kt < 4; ++kt) {
            const int kc2 = (kt * 4 + lk) * 2;       // fp32 16B-chunk pair base
            #pragma unroll
            for (int rf = 0; rf < 4; ++rf) {
                const int R = rf * 16 + l15;
                const char* rb = (const char*)fb + R * 512;
                f32x4 xa = *(const f32x4*)(rb + ((kc2 ^ l15) << 4));
                f32x4 xb = *(const f32x4*)(rb + (((kc2 + 1) ^ l15) << 4));
                union { u32x4 u; s16x8 s; } A;
                A.u[0] = cvt_pk_bf16(xa[0], xa[1]);
                A.u[1] = cvt_pk_bf16(xa[2], xa[3]);
                A.u[2] = cvt_pk_bf16(xb[0], xb[1]);
                A.u[3] = cvt_pk_bf16(xb[2], xb[3]);
                acc[rf][0] = __builtin_amdgcn_mfma_f32_16x16x32_bf16(A.s, bfr[0][kt], acc[rf][0], 0, 0, 0);
                acc[rf][1] = __builtin_amdgcn_mfma_f32_16x16x32_bf16(A.s, bfr[1][kt], acc[rf][1], 0, 0, 0);
            }
        }

        // ---- phase 2a: partial dot with W2, quad-reduce, write pp ----
        #pragma unroll
        for (int rf = 0; rf < 4; ++rf) {
            float pr[4];
            #pragma unroll
            for (int r = 0; r < 4; ++r) {
                float s = 0.f;
                #pragma unroll
                for (int j = 0; j < 2; ++j) {
                    float h = acc[rf][j][r] + b1v[j];
                    h = fmaxf(h, 0.f);
                    s = fmaf(h, w2v[j], s);
                }
                s += __shfl_xor(s, 1, 64);
                s += __shfl_xor(s, 2, 64);
                pr[r] = s;
            }
            float val = pr[0];
            val = ((l & 3) == 1) ? pr[1] : val;
            val = ((l & 3) == 2) ? pr[2] : val;
            val = ((l & 3) == 3) ? pr[3] : val;
            pp[(rf * 16 + lk * 4 + (l & 3)) * PPS + w * 4 + ((l >> 2) & 3)] = val;
        }
        asm volatile("s_waitcnt lgkmcnt(0)" ::: "memory");   // pp flushed
        __builtin_amdgcn_s_barrier();                        // B_pp

        // ---- phase 2b: wave 0 finishes gate ----
        if (tid < TM) {
            float s = 0.f;
            #pragma unroll
            for (int c = 0; c < 16; ++c) s += pp[tid * PPS + c];
            float g = 1.f / (1.f + __expf(-(s + b2s)));
            u32x2 gi; gi[0] = __float_as_uint(g); gi[1] = (uint32_t)ridx;
            gidL[tid] = gi;
        }
        asm volatile("s_waitcnt lgkmcnt(0)" ::: "memory");   // gidL flushed
        __builtin_amdgcn_s_barrier();                        // B_gate

        // ---- phase 3: segmented accumulate of gate*x (fp32 from LDS) ----
        #pragma unroll
        for (int rr = 0; rr < 8; ++rr) {
            const int r = rg * 8 + rr;
            u32x2 gi = gidL[r];
            const int seg = (int)gi[1];
            const float g = __uint_as_float(gi[0]);
            if (seg != cur) {
                if (cur >= 0) {
                    #pragma unroll
                    for (int i = 0; i < 4; ++i)
                        atomicAdd(out + (size_t)cur * D + 4 * cc + i, acc3[i]);
                }
                acc3[0] = acc3[1] = acc3[2] = acc3[3] = 0.f;
                cur = seg;
            }
            f32x4 xw = *(const f32x4*)((const char*)fb + r * 512 + ((cc ^ (r & 15)) << 4));
            acc3[0] = fmaf(g, xw[0], acc3[0]);
            acc3[1] = fmaf(g, xw[1], acc3[1]);
            acc3[2] = fmaf(g, xw[2], acc3[2]);
            acc3[3] = fmaf(g, xw[3], acc3[3]);
        }
        // no end barrier: the next iteration's top barrier separates this
        // phase-3 read of fbuf[cb] from the t+2 issue into fbuf[cb].
    }
    if (cur >= 0) {
        #pragma unroll
        for (int i = 0; i < 4; ++i)
            atomicAdd(out + (size_t)cur * D + 4 * cc + i, acc3[i]);
    }
}

extern "C" void kernel_launch(void* const* d_in, const int* in_sizes, int n_in,
                              void* d_out, int out_size, void* d_ws, size_t ws_size,
                              hipStream_t stream) {
    const float* X    = (const float*)d_in[0];
    const int*   bidx = (const int*)d_in[1];
    const float* W1   = (const float*)d_in[2];
    const float* b1   = (const float*)d_in[3];
    const float* W2   = (const float*)d_in[4];
    const float* b2   = (const float*)d_in[5];
    float* out = (float*)d_out;

    const int N  = in_sizes[0] / D;      // 1,000,000
    const int NT = N / TM;               // 15,625 tiles

    hipMemsetAsync(d_out, 0, (size_t)out_size * sizeof(float), stream);
    gate_agg_kernel<<<GRID, NTHREADS, 0, stream>>>(X, bidx, W1, b1, W2, b2, out, NT);
}

// Round 6
// 113.844 us; speedup vs baseline: 1.1747x; 1.1747x over previous
//
#include <hip/hip_runtime.h>
#include <stdint.h>

#define D 128
#define TM 64
#define GRID 512        // 2 blocks/CU (LDS-capped: 66 KB/block)
#define NTHREADS 256

typedef float f32x4 __attribute__((ext_vector_type(4)));
typedef short s16x8 __attribute__((ext_vector_type(8)));
typedef uint32_t u32x2 __attribute__((ext_vector_type(2)));

__device__ __forceinline__ uint32_t f2bf_u(float f) {
    union { float f; uint32_t u; } v; v.f = f;
    return (v.u + 0x7fffu + ((v.u >> 16) & 1u)) >> 16;   // RNE
}
__device__ __forceinline__ short f2bf(float f) { return (short)f2bf_u(f); }
__device__ __forceinline__ uint32_t cvt_pk_bf16(float lo, float hi) {
    uint32_t r;
    asm("v_cvt_pk_bf16_f32 %0, %1, %2" : "=v"(r) : "v"(lo), "v"(hi));
    return r;
}

__global__ __launch_bounds__(NTHREADS, 2)
void gate_agg_kernel(const float* __restrict__ X,
                     const int* __restrict__ bidx,
                     const float* __restrict__ W1,
                     const float* __restrict__ b1,
                     const float* __restrict__ W2,
                     const float* __restrict__ b2,
                     float* __restrict__ out,
                     int NT)
{
    __shared__ short w1p[16 * D * 8];      // bf16 B-frags [k>>3][n][k&7], 32 KB
    __shared__ short xt[2][TM * D];        // bf16 tiles, swizzled, 2 x 16 KB
    __shared__ u32x2 gidW[TM];             // wave w uses [16w..16w+15]; same-wave only

    const int tid = threadIdx.x;
    const int l = tid & 63;
    const int w = tid >> 6;
    const int l15 = l & 15;
    const int lk = l >> 4;

    // ---- one-time: pack W1 -> bf16 LDS B-fragment layout
    for (int i = tid; i < D * D; i += NTHREADS) {
        int k = i >> 7, n = i & 127;
        w1p[(((k >> 3) * D) + n) * 8 + (k & 7)] = f2bf(W1[i]);
    }
    float b1v[8], w2v[8];
    #pragma unroll
    for (int ct = 0; ct < 8; ++ct) {
        b1v[ct] = b1[ct * 16 + l15];
        w2v[ct] = W2[ct * 16 + l15];
    }
    const float b2s = b2[0];

    // balanced contiguous tile range
    const int q = NT / GRID, rem = NT % GRID;
    int t0, t1;
    if ((int)blockIdx.x < rem) { t0 = blockIdx.x * (q + 1); t1 = t0 + q + 1; }
    else { t0 = rem * (q + 1) + ((int)blockIdx.x - rem) * q; t1 = t0 + q; }

    // phase-3: wave w owns rows 16w..16w+15; lane owns cols 2l, 2l+1
    float acc3[2] = {0.f, 0.f};
    int cur = -1;

    // ---- prologue: depth-2 prefetch (vA = t0, vB = t0+1)
    f32x4 vA[8], vB[8];
    int ridxA = 0, ridxB = 0;
    if (t0 < t1) {
        const float* xg = X + (size_t)t0 * TM * D;
        #pragma unroll
        for (int j = 0; j < 8; ++j) vA[j] = *(const f32x4*)(xg + (size_t)(j * 256 + tid) * 4);
        if (l < 16) ridxA = bidx[(size_t)t0 * TM + 16 * w + l];
    }
    if (t0 + 1 < t1) {
        const float* xg = X + (size_t)(t0 + 1) * TM * D;
        #pragma unroll
        for (int j = 0; j < 8; ++j) vB[j] = *(const f32x4*)(xg + (size_t)(j * 256 + tid) * 4);
        if (l < 16) ridxB = bidx[(size_t)(t0 + 1) * TM + 16 * w + l];
    }

    asm volatile("s_waitcnt lgkmcnt(0)" ::: "memory");   // w1p packed
    __builtin_amdgcn_s_barrier();

#define BODY(V, RIDX, PB)                                                        \
    {                                                                            \
        /* stage V -> xt[PB] (compiler waits vmcnt for V only: counted) */       \
        _Pragma("unroll")                                                        \
        for (int j = 0; j < 8; ++j) {                                            \
            int qc = j * 256 + tid;                                              \
            int row = qc >> 5, cq = qc & 31;                                     \
            int c2 = cq >> 1, h = cq & 1;                                        \
            u32x2 wv;                                                            \
            wv[0] = cvt_pk_bf16(V[j][0], V[j][1]);                               \
            wv[1] = cvt_pk_bf16(V[j][2], V[j][3]);                               \
            *(u32x2*)((char*)xt[PB] + row * 256 + ((c2 ^ (row & 15)) << 4) + h * 8) = wv; \
        }                                                                        \
        const int ridx_cur = RIDX;                                               \
        /* depth-2: issue tile t+2 into the just-freed regs */                   \
        if (t + 2 < t1) {                                                        \
            const float* xg = X + (size_t)(t + 2) * TM * D;                      \
            _Pragma("unroll")                                                    \
            for (int j = 0; j < 8; ++j)                                          \
                V[j] = *(const f32x4*)(xg + (size_t)(j * 256 + tid) * 4);        \
            if (l < 16) RIDX = bidx[(size_t)(t + 2) * TM + 16 * w + l];          \
        }                                                                        \
        asm volatile("s_waitcnt lgkmcnt(0)" ::: "memory");                       \
        __builtin_amdgcn_s_barrier();                                            \
        __builtin_amdgcn_sched_barrier(0);                                       \
        /* phase 1: wave's 16 rows x 128 cols, MFMA */                           \
        f32x4 acc[8];                                                            \
        _Pragma("unroll")                                                        \
        for (int ct = 0; ct < 8; ++ct) acc[ct] = (f32x4)0.f;                     \
        {                                                                        \
            const int R = 16 * w + l15;                                          \
            const char* rb = (const char*)xt[PB] + R * 256;                      \
            _Pragma("unroll")                                                    \
            for (int kt = 0; kt < 4; ++kt) {                                     \
                const int kc = kt * 4 + lk;                                      \
                s16x8 a = *(const s16x8*)(rb + ((kc ^ l15) << 4));               \
                _Pragma("unroll")                                                \
                for (int ct = 0; ct < 8; ++ct) {                                 \
                    s16x8 bf = *(const s16x8*)&w1p[(kc * D + ct * 16 + l15) * 8];\
                    acc[ct] = __builtin_amdgcn_mfma_f32_16x16x32_bf16(a, bf, acc[ct], 0, 0, 0); \
                }                                                                \
            }                                                                    \
        }                                                                        \
        /* phase 2: in-wave gate; {g,seg} via per-wave LDS (no barrier) */       \
        {                                                                        \
            float p[4] = {0.f, 0.f, 0.f, 0.f};                                   \
            _Pragma("unroll")                                                    \
            for (int ct = 0; ct < 8; ++ct) {                                     \
                _Pragma("unroll")                                                \
                for (int r = 0; r < 4; ++r) {                                    \
                    float h = acc[ct][r] + b1v[ct];                              \
                    h = fmaxf(h, 0.f);                                           \
                    p[r] = fmaf(h, w2v[ct], p[r]);                               \
                }                                                                \
            }                                                                    \
            _Pragma("unroll")                                                    \
            for (int r = 0; r < 4; ++r) {                                        \
                p[r] += __shfl_xor(p[r], 1, 64);                                 \
                p[r] += __shfl_xor(p[r], 2, 64);                                 \
                p[r] += __shfl_xor(p[r], 4, 64);                                 \
                p[r] += __shfl_xor(p[r], 8, 64);                                 \
            }                                                                    \
            const int sel = l15;                                                 \
            float ps = p[0];                                                     \
            ps = (sel == 1) ? p[1] : ps;                                         \
            ps = (sel == 2) ? p[2] : ps;                                         \
            ps = (sel == 3) ? p[3] : ps;                                         \
            const int rr = lk * 4 + sel;          /* strip row, valid sel<4 */   \
            const int seg = __shfl(ridx_cur, rr & 15, 64);                       \
            if (sel < 4) {                                                       \
                float g = 1.f / (1.f + __expf(-(ps + b2s)));                     \
                u32x2 gi; gi[0] = __float_as_uint(g); gi[1] = (uint32_t)seg;     \
                gidW[16 * w + rr] = gi;                                          \
            }                                                                    \
        }                                                                        \
        /* phase 3: segmented accumulate over the wave's 16 rows */              \
        _Pragma("unroll")                                                        \
        for (int r = 0; r < 16; ++r) {                                           \
            u32x2 gi = gidW[16 * w + r];                                         \
            const int seg = (int)gi[1];                                          \
            const float g = __uint_as_float(gi[0]);                              \
            if (seg != cur) {                                                    \
                if (cur >= 0) {                                                  \
                    atomicAdd(out + (size_t)cur * D + 2 * l,     acc3[0]);       \
                    atomicAdd(out + (size_t)cur * D + 2 * l + 1, acc3[1]);       \
                }                                                                \
                acc3[0] = 0.f; acc3[1] = 0.f; cur = seg;                         \
            }                                                                    \
            const int Rr = 16 * w + r;                                           \
            uint32_t xw = *(const uint32_t*)((const char*)xt[PB] + Rr * 256 +    \
                           ((((l >> 2) ^ (Rr & 15)) << 4)) + (l & 3) * 4);       \
            acc3[0] = fmaf(g, __uint_as_float(xw << 16),          acc3[0]);      \
            acc3[1] = fmaf(g, __uint_as_float(xw & 0xffff0000u),  acc3[1]);      \
        }                                                                        \
    }

    int t = t0;
    while (t < t1) {
        BODY(vA, ridxA, 0);
        ++t; if (t >= t1) break;
        BODY(vB, ridxB, 1);
        ++t;
    }
#undef BODY

    if (cur >= 0) {
        atomicAdd(out + (size_t)cur * D + 2 * l,     acc3[0]);
        atomicAdd(out + (size_t)cur * D + 2 * l + 1, acc3[1]);
    }
}

extern "C" void kernel_launch(void* const* d_in, const int* in_sizes, int n_in,
                              void* d_out, int out_size, void* d_ws, size_t ws_size,
                              hipStream_t stream) {
    const float* X    = (const float*)d_in[0];
    const int*   bidx = (const int*)d_in[1];
    const float* W1   = (const float*)d_in[2];
    const float* b1   = (const float*)d_in[3];
    const float* W2   = (const float*)d_in[4];
    const float* b2   = (const float*)d_in[5];
    float* out = (float*)d_out;

    const int N  = in_sizes[0] / D;      // 1,000,000
    const int NT = N / TM;               // 15,625 tiles

    hipMemsetAsync(d_out, 0, (size_t)out_size * sizeof(float), stream);
    gate_agg_kernel<<<GRID, NTHREADS, 0, stream>>>(X, bidx, W1, b1, W2, b2, out, NT);
}